// Round 2
// baseline (1788.776 us; speedup 1.0000x reference)
//
#include <hip/hip_runtime.h>
#include <cstdint>
#include <cstddef>

#define B_SZ 2
#define S_LEN 2048
#define CTX_LEN 512
#define DIM 1536
#define NH 12
#define HD 128
#define FFN_D 6144
#define NE 4
#define TOPK 2

typedef unsigned short u16;
typedef __attribute__((ext_vector_type(8))) __bf16 bf16x8;
typedef __attribute__((ext_vector_type(4))) float f32x4;
typedef __attribute__((ext_vector_type(4))) unsigned short u16x4;

__device__ __forceinline__ u16 f2bf(float f) {
  union { float f; uint32_t u; } un; un.f = f;
  uint32_t u = un.u;
  u += 0x7fffu + ((u >> 16) & 1u);   // RNE
  return (u16)(u >> 16);
}

// ---------------- f32 -> bf16 convert (weights, context) ----------------
__global__ void cvt_f32_bf16(const float* __restrict__ src, u16* __restrict__ dst, int n4) {
  int i = blockIdx.x * blockDim.x + threadIdx.x;
  int stride = gridDim.x * blockDim.x;
  for (; i < n4; i += stride) {
    f32x4 v = ((const f32x4*)src)[i];
    u16x4 o;
    o.x = f2bf(v.x); o.y = f2bf(v.y); o.z = f2bf(v.z); o.w = f2bf(v.w);
    ((u16x4*)dst)[i] = o;
  }
}

// ---------------- LayerNorm (+AdaLN modulation or affine) -> bf16 ----------------
// MODE 0: y = ln(x) * (1 + mod[scale_idx]) + mod[shift_idx]   (mod = modulation + t_mod)
// MODE 1: y = ln(x) * w + b
template<int MODE>
__global__ __launch_bounds__(256) void ln_mod_kernel(
    const float* __restrict__ x, u16* __restrict__ out,
    const float* __restrict__ modv, const float* __restrict__ tmod,
    int scale_idx, int shift_idx,
    const float* __restrict__ w, const float* __restrict__ bvec)
{
  __shared__ float rbuf[8];
  int row = blockIdx.x;
  int b = row / S_LEN;
  const float* xr = x + (size_t)row * DIM;
  float v[6];
  float s = 0.f, s2 = 0.f;
#pragma unroll
  for (int j = 0; j < 6; ++j) {
    float t = xr[threadIdx.x + j * 256];
    v[j] = t; s += t; s2 += t * t;
  }
#pragma unroll
  for (int m = 32; m > 0; m >>= 1) { s += __shfl_xor(s, m, 64); s2 += __shfl_xor(s2, m, 64); }
  int wid = threadIdx.x >> 6;
  if ((threadIdx.x & 63) == 0) { rbuf[wid] = s; rbuf[4 + wid] = s2; }
  __syncthreads();
  s  = rbuf[0] + rbuf[1] + rbuf[2] + rbuf[3];
  s2 = rbuf[4] + rbuf[5] + rbuf[6] + rbuf[7];
  float mean = s * (1.f / DIM);
  float var  = s2 * (1.f / DIM) - mean * mean;
  float rstd = rsqrtf(var + 1e-6f);
#pragma unroll
  for (int j = 0; j < 6; ++j) {
    int n = threadIdx.x + j * 256;
    float y = (v[j] - mean) * rstd;
    float mul, add;
    if (MODE == 0) {
      mul = 1.f + modv[scale_idx * DIM + n] + tmod[(b * 6 + scale_idx) * DIM + n];
      add = modv[shift_idx * DIM + n] + tmod[(b * 6 + shift_idx) * DIM + n];
    } else {
      mul = w[n]; add = bvec[n];
    }
    out[(size_t)row * DIM + n] = f2bf(y * mul + add);
  }
}

// ---------------- RMSNorm (+optional RoPE) f32 -> bf16 ----------------
template<int ROPE>
__global__ __launch_bounds__(256) void rms_rope_kernel(
    const float* __restrict__ x, const float* __restrict__ w,
    const float* __restrict__ cosb, const float* __restrict__ sinb,
    u16* __restrict__ out)
{
  __shared__ float rbuf[4];
  int row = blockIdx.x;
  const float* xr = x + (size_t)row * DIM;
  float v[6];
  float s2 = 0.f;
#pragma unroll
  for (int j = 0; j < 6; ++j) { float t = xr[threadIdx.x + j * 256]; v[j] = t; s2 += t * t; }
#pragma unroll
  for (int m = 32; m > 0; m >>= 1) s2 += __shfl_xor(s2, m, 64);
  int wid = threadIdx.x >> 6;
  if ((threadIdx.x & 63) == 0) rbuf[wid] = s2;
  __syncthreads();
  s2 = rbuf[0] + rbuf[1] + rbuf[2] + rbuf[3];
  float rs = rsqrtf(s2 * (1.f / DIM) + 1e-6f);
  if (ROPE) {
    int spos = row & (S_LEN - 1);
#pragma unroll
    for (int j = 0; j < 3; ++j) {
      int pr = threadIdx.x + j * 256;          // pair index 0..767
      int head = pr >> 6, d = pr & 63;
      int n0 = head * HD + 2 * d;
      float xa = xr[n0] * rs * w[n0];
      float xb = xr[n0 + 1] * rs * w[n0 + 1];
      float c = cosb[spos * 64 + d], sn = sinb[spos * 64 + d];
      out[(size_t)row * DIM + n0]     = f2bf(xa * c - xb * sn);
      out[(size_t)row * DIM + n0 + 1] = f2bf(xa * sn + xb * c);
    }
  } else {
#pragma unroll
    for (int j = 0; j < 6; ++j) {
      int n = threadIdx.x + j * 256;
      out[(size_t)row * DIM + n] = f2bf(v[j] * rs * w[n]);
    }
  }
}

// ---------------- bf16 MFMA GEMM: C[M,N] = A[M,K] @ W[N,K]^T + bias, fused epilogues ----------------
// EPI 0: f32 out               EPI 1: bf16 out
// EPI 2: gelu(tanh) bf16 out   EPI 3: f32 out = res + gate_mod*(v)
// EPI 4: f32 out = res + v     EPI 5: f32 out += moe_weight(row,expert)*v
#define BKP 40   // padded LDS row stride (elements): 80B -> conflict-free b128 reads

template<int EPI>
__global__ __launch_bounds__(256) void gemm_bt(
    const u16* __restrict__ A, const u16* __restrict__ W,
    const float* __restrict__ bias, void* __restrict__ Cout,
    const float* __restrict__ res,
    const float* __restrict__ modv, const float* __restrict__ tmod, int mod_idx,
    const float* __restrict__ ew, const int* __restrict__ topk, int expert,
    int M, int N, int K)
{
  __shared__ __align__(16) u16 As[128 * BKP];
  __shared__ __align__(16) u16 Bs[128 * BKP];
  int tid = threadIdx.x;
  int wid = tid >> 6, lane = tid & 63;
  int wr = wid >> 1, wc = wid & 1;
  size_t brow = (size_t)blockIdx.x * 128, bcol = (size_t)blockIdx.y * 128;

  f32x4 acc[4][4];
#pragma unroll
  for (int i = 0; i < 4; ++i)
#pragma unroll
    for (int j = 0; j < 4; ++j) acc[i][j] = (f32x4){0.f, 0.f, 0.f, 0.f};

  // staging map: thread covers two 8-elem chunks of the 128x32 tile
  int flat0 = (wid * 64 + lane) * 8;
  int flat1 = flat0 + 2048;
  int r0 = flat0 >> 5, c0 = flat0 & 31;
  int r1 = flat1 >> 5, c1 = flat1 & 31;
  const u16* Ab0 = A + (brow + r0) * (size_t)K + c0;
  const u16* Ab1 = A + (brow + r1) * (size_t)K + c1;
  const u16* Wb0 = W + (bcol + r0) * (size_t)K + c0;
  const u16* Wb1 = W + (bcol + r1) * (size_t)K + c1;

  int cl = lane & 15, kk = (lane >> 4) * 8;

  for (int k0 = 0; k0 < K; k0 += 32) {
    bf16x8 a0 = *(const bf16x8*)(Ab0 + k0);
    bf16x8 a1 = *(const bf16x8*)(Ab1 + k0);
    bf16x8 b0 = *(const bf16x8*)(Wb0 + k0);
    bf16x8 b1 = *(const bf16x8*)(Wb1 + k0);
    __syncthreads();                 // prior iter's LDS reads done
    *(bf16x8*)&As[r0 * BKP + c0] = a0;
    *(bf16x8*)&As[r1 * BKP + c1] = a1;
    *(bf16x8*)&Bs[r0 * BKP + c0] = b0;
    *(bf16x8*)&Bs[r1 * BKP + c1] = b1;
    __syncthreads();
    bf16x8 af[4], bw[4];
#pragma unroll
    for (int i = 0; i < 4; ++i) {
      af[i] = *(const bf16x8*)&As[(wr * 64 + i * 16 + cl) * BKP + kk];
      bw[i] = *(const bf16x8*)&Bs[(wc * 64 + i * 16 + cl) * BKP + kk];
    }
#pragma unroll
    for (int mi = 0; mi < 4; ++mi)
#pragma unroll
      for (int ni = 0; ni < 4; ++ni)
        acc[mi][ni] = __builtin_amdgcn_mfma_f32_16x16x32_bf16(af[mi], bw[ni], acc[mi][ni], 0, 0, 0);
  }

  size_t row_base = brow + wr * 64;
  size_t col_base = bcol + wc * 64;
  int g4 = (lane >> 4) * 4;
#pragma unroll
  for (int ni = 0; ni < 4; ++ni) {
    size_t col = col_base + ni * 16 + cl;
    float bv = bias[col];
#pragma unroll
    for (int mi = 0; mi < 4; ++mi) {
#pragma unroll
      for (int r = 0; r < 4; ++r) {
        size_t row = row_base + mi * 16 + g4 + r;
        float val = acc[mi][ni][r] + bv;
        size_t idx = row * (size_t)N + col;
        if (EPI == 0) {
          ((float*)Cout)[idx] = val;
        } else if (EPI == 1) {
          ((u16*)Cout)[idx] = f2bf(val);
        } else if (EPI == 2) {
          float g = 0.5f * val * (1.f + tanhf(0.7978845608028654f * (val + 0.044715f * val * val * val)));
          ((u16*)Cout)[idx] = f2bf(g);
        } else if (EPI == 3) {
          int bb = (int)(row / S_LEN);
          float gate = modv[mod_idx * DIM + col] + tmod[((size_t)bb * 6 + mod_idx) * DIM + col];
          ((float*)Cout)[idx] = res[idx] + gate * val;
        } else if (EPI == 4) {
          ((float*)Cout)[idx] = res[idx] + val;
        } else if (EPI == 5) {
          float wsum = 0.f;
          int t0 = topk[row * TOPK], t1 = topk[row * TOPK + 1];
          if (t0 == expert) wsum += ew[row * TOPK];
          if (t1 == expert) wsum += ew[row * TOPK + 1];
          if (wsum != 0.f) ((float*)Cout)[idx] += wsum * val;
        }
      }
    }
  }
}

// ---------------- per-head V transpose: vt[b,h,d,s] = v[b,s,h*HD+d] ----------------
__global__ void transpose_v_kernel(const u16* __restrict__ v, u16* __restrict__ vt, int slen) {
  __shared__ u16 t[32][33];
  int bh = blockIdx.z;
  int b = bh / NH, h = bh % NH;
  int s0 = blockIdx.x * 32, d0 = blockIdx.y * 32;
  t[threadIdx.y][threadIdx.x] =
      v[((size_t)(b * slen) + s0 + threadIdx.y) * DIM + h * HD + d0 + threadIdx.x];
  __syncthreads();
  vt[((size_t)bh * HD + d0 + threadIdx.y) * slen + s0 + threadIdx.x] = t[threadIdx.x][threadIdx.y];
}

// ---------------- flash attention (bf16 in, bf16 out, f32 online softmax) ----------------
// grid: (sq/64, B*NH); block 256 = 4 waves; each wave owns 16 q rows; 32 keys/iter
__global__ __launch_bounds__(256) void flash_attn_kernel(
    const u16* __restrict__ q, const u16* __restrict__ k,
    const u16* __restrict__ vt, u16* __restrict__ out,
    int sq, int sk)
{
  __shared__ __align__(16) u16 p_lds[4][16][32];
  int tid = threadIdx.x;
  int wid = tid >> 6, lane = tid & 63;
  int cl = lane & 15, g = lane >> 4;
  int bh = blockIdx.y, b = bh / NH, h = bh % NH;
  int q0 = blockIdx.x * 64 + wid * 16;

  const u16* qp = q + ((size_t)(b * sq) + q0 + cl) * DIM + h * HD + g * 8;
  bf16x8 aq[4];
#pragma unroll
  for (int c = 0; c < 4; ++c) aq[c] = *(const bf16x8*)(qp + c * 32);

  f32x4 o[8];
#pragma unroll
  for (int i = 0; i < 8; ++i) o[i] = (f32x4){0.f, 0.f, 0.f, 0.f};
  float m_r[4] = {-1e30f, -1e30f, -1e30f, -1e30f};
  float l_r[4] = {0.f, 0.f, 0.f, 0.f};
  const float sc = 0.08838834764831845f;  // 1/sqrt(128)

  const u16* kb = k + (size_t)(b * sk) * DIM + h * HD;
  const u16* vb = vt + (size_t)bh * HD * sk;

  for (int kt = 0; kt < sk; kt += 32) {
    f32x4 s0v = (f32x4){0.f, 0.f, 0.f, 0.f};
    f32x4 s1v = (f32x4){0.f, 0.f, 0.f, 0.f};
    const u16* kp0 = kb + (size_t)(kt + cl) * DIM + g * 8;
    const u16* kp1 = kp0 + (size_t)16 * DIM;
#pragma unroll
    for (int c = 0; c < 4; ++c) {
      bf16x8 bk0 = *(const bf16x8*)(kp0 + c * 32);
      bf16x8 bk1 = *(const bf16x8*)(kp1 + c * 32);
      s0v = __builtin_amdgcn_mfma_f32_16x16x32_bf16(aq[c], bk0, s0v, 0, 0, 0);
      s1v = __builtin_amdgcn_mfma_f32_16x16x32_bf16(aq[c], bk1, s1v, 0, 0, 0);
    }
    float p0[4], p1[4];
#pragma unroll
    for (int r = 0; r < 4; ++r) {
      float v0 = s0v[r] * sc, v1 = s1v[r] * sc;
      float pm = fmaxf(v0, v1);
#pragma unroll
      for (int msk = 8; msk > 0; msk >>= 1) pm = fmaxf(pm, __shfl_xor(pm, msk, 64));
      float mn = fmaxf(m_r[r], pm);
      float cf = __expf(m_r[r] - mn);
      float e0 = __expf(v0 - mn), e1 = __expf(v1 - mn);
      float rsum = e0 + e1;
#pragma unroll
      for (int msk = 8; msk > 0; msk >>= 1) rsum += __shfl_xor(rsum, msk, 64);
      l_r[r] = l_r[r] * cf + rsum;
      m_r[r] = mn;
      p0[r] = e0; p1[r] = e1;
#pragma unroll
      for (int cc = 0; cc < 8; ++cc) o[cc][r] *= cf;
    }
    // D-layout -> A-layout bounce through LDS (per-wave private tile)
#pragma unroll
    for (int r = 0; r < 4; ++r) {
      p_lds[wid][g * 4 + r][cl]      = f2bf(p0[r]);
      p_lds[wid][g * 4 + r][16 + cl] = f2bf(p1[r]);
    }
    asm volatile("s_waitcnt lgkmcnt(0)" ::: "memory");
    bf16x8 ap = *(const bf16x8*)&p_lds[wid][cl][g * 8];
    const u16* vp = vb + (size_t)cl * sk + kt + g * 8;
#pragma unroll
    for (int cc = 0; cc < 8; ++cc) {
      bf16x8 bv = *(const bf16x8*)(vp + (size_t)cc * 16 * sk);
      o[cc] = __builtin_amdgcn_mfma_f32_16x16x32_bf16(ap, bv, o[cc], 0, 0, 0);
    }
  }
#pragma unroll
  for (int r = 0; r < 4; ++r) {
    float inv = 1.f / l_r[r];
    size_t orow = (size_t)(b * sq) + q0 + g * 4 + r;
#pragma unroll
    for (int cc = 0; cc < 8; ++cc)
      out[orow * DIM + h * HD + cc * 16 + cl] = f2bf(o[cc][r] * inv);
  }
}

// ---------------- final: out = xb + gate_mlp * (ff + moe) ----------------
__global__ __launch_bounds__(256) void final_add_kernel(
    const float* __restrict__ xb, float* __restrict__ out,
    const float* __restrict__ modv, const float* __restrict__ tmod)
{
  size_t i4 = (size_t)blockIdx.x * 256 + threadIdx.x;
  size_t base = i4 * 4;
  int n = (int)(base % DIM);
  int b = (int)(base / ((size_t)S_LEN * DIM));
  f32x4 xv = ((const f32x4*)xb)[i4];
  f32x4 ov = ((const f32x4*)out)[i4];
  f32x4 r;
#pragma unroll
  for (int j = 0; j < 4; ++j) {
    float gate = modv[5 * DIM + n + j] + tmod[((size_t)b * 6 + 5) * DIM + n + j];
    r[j] = xv[j] + gate * ov[j];
  }
  ((f32x4*)out)[i4] = r;
}

// =========================== host ===========================
extern "C" void kernel_launch(void* const* d_in, const int* in_sizes, int n_in,
                              void* d_out, int out_size, void* d_ws, size_t ws_size,
                              hipStream_t stream) {
  (void)in_sizes; (void)n_in; (void)out_size; (void)ws_size;
  const float* x_in   = (const float*)d_in[0];
  const float* ctx_in = (const float*)d_in[1];
  const float* tmod   = (const float*)d_in[2];
  const float* fcos   = (const float*)d_in[3];
  const float* fsin   = (const float*)d_in[4];
  const float* ew     = (const float*)d_in[5];
  const int*   topk   = (const int*)d_in[6];
  const float* sa_q_w = (const float*)d_in[7];
  const float* sa_q_b = (const float*)d_in[8];
  const float* sa_k_w = (const float*)d_in[9];
  const float* sa_k_b = (const float*)d_in[10];
  const float* sa_v_w = (const float*)d_in[11];
  const float* sa_v_b = (const float*)d_in[12];
  const float* sa_o_w = (const float*)d_in[13];
  const float* sa_o_b = (const float*)d_in[14];
  const float* sa_nq_w = (const float*)d_in[15];
  const float* sa_nk_w = (const float*)d_in[16];
  const float* ca_q_w = (const float*)d_in[17];
  const float* ca_q_b = (const float*)d_in[18];
  const float* ca_k_w = (const float*)d_in[19];
  const float* ca_k_b = (const float*)d_in[20];
  const float* ca_v_w = (const float*)d_in[21];
  const float* ca_v_b = (const float*)d_in[22];
  const float* ca_o_w = (const float*)d_in[23];
  const float* ca_o_b = (const float*)d_in[24];
  const float* ca_nq_w = (const float*)d_in[25];
  const float* ca_nk_w = (const float*)d_in[26];
  const float* norm3_w = (const float*)d_in[27];
  const float* norm3_b = (const float*)d_in[28];
  const float* ffn_w1 = (const float*)d_in[29];
  const float* ffn_b1 = (const float*)d_in[30];
  const float* ffn_w2 = (const float*)d_in[31];
  const float* ffn_b2 = (const float*)d_in[32];
  const float* modv   = (const float*)d_in[33];
  const float* moe_w  = (const float*)d_in[34];
  const float* moe_b  = (const float*)d_in[35];

  char* p = (char*)d_ws;
  auto alloc = [&](size_t bytes) { void* r = (void*)p; p += ((bytes + 255) & ~(size_t)255); return r; };
  const size_t NTOK = (size_t)B_SZ * S_LEN;          // 4096
  const size_t NCTX = (size_t)B_SZ * CTX_LEN;        // 1024
  const size_t DD = (size_t)DIM * DIM;

  // persistent weights (bf16)
  u16* w_saq  = (u16*)alloc(DD * 2);
  u16* w_sak  = (u16*)alloc(DD * 2);
  u16* w_sav  = (u16*)alloc(DD * 2);
  u16* w_sao  = (u16*)alloc(DD * 2);
  u16* w_caq  = (u16*)alloc(DD * 2);
  u16* w_cak  = (u16*)alloc(DD * 2);
  u16* w_cav  = (u16*)alloc(DD * 2);
  u16* w_cao  = (u16*)alloc(DD * 2);
  u16* w_ffn1 = (u16*)alloc((size_t)FFN_D * DIM * 2);
  u16* w_ffn2 = (u16*)alloc((size_t)DIM * FFN_D * 2);
  u16* w_moe  = (u16*)alloc((size_t)NE * DD * 2);
  // activations
  u16* h_bf   = (u16*)alloc(NTOK * DIM * 2);
  float* raw  = (float*)alloc(NTOK * DIM * 4);
  float* xb   = (float*)alloc(NTOK * DIM * 4);
  u16* q_bf   = (u16*)alloc(NTOK * DIM * 2);   // NOTE: q,k,v,vt contiguous (each mult of 256B)
  u16* k_bf   = (u16*)alloc(NTOK * DIM * 2);
  u16* v_bf   = (u16*)alloc(NTOK * DIM * 2);
  u16* vt_bf  = (u16*)alloc(NTOK * DIM * 2);
  u16* ctx_bf = (u16*)alloc(NCTX * DIM * 2);
  u16* ck_bf  = (u16*)alloc(NCTX * DIM * 2);
  u16* cv_bf  = (u16*)alloc(NCTX * DIM * 2);
  // aliases (live-range verified):
  u16* attn_bf = (u16*)raw;   // raw (f32 pre-norm scratch) is dead when attention output lands
  u16* ff1_bf  = q_bf;        // FFN phase: q..vt region (4 x 12.58MB = 50.33MB) is dead

  auto cvtl = [&](const float* s_, u16* d_, size_t n) {
    int n4 = (int)(n / 4);
    int nb = (n4 + 255) / 256; if (nb > 2048) nb = 2048;
    cvt_f32_bf16<<<nb, 256, 0, stream>>>(s_, d_, n4);
  };
  auto GEMM = [&](int epi, const u16* Aa, const u16* Ww, const float* bb, void* Cc,
                  const float* rr, int mod_idx, int expert, int M, int N, int K) {
    dim3 g(M / 128, N / 128);
    switch (epi) {
      case 0: gemm_bt<0><<<g, 256, 0, stream>>>(Aa, Ww, bb, Cc, rr, modv, tmod, mod_idx, ew, topk, expert, M, N, K); break;
      case 1: gemm_bt<1><<<g, 256, 0, stream>>>(Aa, Ww, bb, Cc, rr, modv, tmod, mod_idx, ew, topk, expert, M, N, K); break;
      case 2: gemm_bt<2><<<g, 256, 0, stream>>>(Aa, Ww, bb, Cc, rr, modv, tmod, mod_idx, ew, topk, expert, M, N, K); break;
      case 3: gemm_bt<3><<<g, 256, 0, stream>>>(Aa, Ww, bb, Cc, rr, modv, tmod, mod_idx, ew, topk, expert, M, N, K); break;
      case 4: gemm_bt<4><<<g, 256, 0, stream>>>(Aa, Ww, bb, Cc, rr, modv, tmod, mod_idx, ew, topk, expert, M, N, K); break;
      case 5: gemm_bt<5><<<g, 256, 0, stream>>>(Aa, Ww, bb, Cc, rr, modv, tmod, mod_idx, ew, topk, expert, M, N, K); break;
    }
  };

  // weight/context conversion
  cvtl(sa_q_w, w_saq, DD); cvtl(sa_k_w, w_sak, DD); cvtl(sa_v_w, w_sav, DD); cvtl(sa_o_w, w_sao, DD);
  cvtl(ca_q_w, w_caq, DD); cvtl(ca_k_w, w_cak, DD); cvtl(ca_v_w, w_cav, DD); cvtl(ca_o_w, w_cao, DD);
  cvtl(ffn_w1, w_ffn1, (size_t)FFN_D * DIM);
  cvtl(ffn_w2, w_ffn2, (size_t)DIM * FFN_D);
  cvtl(moe_w, w_moe, (size_t)NE * DD);
  cvtl(ctx_in, ctx_bf, NCTX * DIM);

  // ---- self attention ----
  ln_mod_kernel<0><<<(int)NTOK, 256, 0, stream>>>(x_in, h_bf, modv, tmod, 1, 0, nullptr, nullptr);
  GEMM(0, h_bf, w_saq, sa_q_b, raw, nullptr, 0, 0, (int)NTOK, DIM, DIM);
  rms_rope_kernel<1><<<(int)NTOK, 256, 0, stream>>>(raw, sa_nq_w, fcos, fsin, q_bf);
  GEMM(0, h_bf, w_sak, sa_k_b, raw, nullptr, 0, 0, (int)NTOK, DIM, DIM);
  rms_rope_kernel<1><<<(int)NTOK, 256, 0, stream>>>(raw, sa_nk_w, fcos, fsin, k_bf);
  GEMM(1, h_bf, w_sav, sa_v_b, v_bf, nullptr, 0, 0, (int)NTOK, DIM, DIM);
  transpose_v_kernel<<<dim3(S_LEN / 32, HD / 32, B_SZ * NH), dim3(32, 32), 0, stream>>>(v_bf, vt_bf, S_LEN);
  flash_attn_kernel<<<dim3(S_LEN / 64, B_SZ * NH), 256, 0, stream>>>(q_bf, k_bf, vt_bf, attn_bf, S_LEN, S_LEN);
  GEMM(3, attn_bf, w_sao, sa_o_b, xb, x_in, 2, 0, (int)NTOK, DIM, DIM);   // xb = x + gate_msa*(...)

  // ---- cross attention ----
  ln_mod_kernel<1><<<(int)NTOK, 256, 0, stream>>>(xb, h_bf, nullptr, nullptr, 0, 0, norm3_w, norm3_b);
  GEMM(0, h_bf, w_caq, ca_q_b, raw, nullptr, 0, 0, (int)NTOK, DIM, DIM);
  rms_rope_kernel<0><<<(int)NTOK, 256, 0, stream>>>(raw, ca_nq_w, fcos, fsin, q_bf);
  GEMM(0, ctx_bf, w_cak, ca_k_b, raw, nullptr, 0, 0, (int)NCTX, DIM, DIM);
  rms_rope_kernel<0><<<(int)NCTX, 256, 0, stream>>>(raw, ca_nk_w, fcos, fsin, ck_bf);
  GEMM(1, ctx_bf, w_cav, ca_v_b, cv_bf, nullptr, 0, 0, (int)NCTX, DIM, DIM);
  transpose_v_kernel<<<dim3(CTX_LEN / 32, HD / 32, B_SZ * NH), dim3(32, 32), 0, stream>>>(cv_bf, vt_bf, CTX_LEN);
  flash_attn_kernel<<<dim3(S_LEN / 64, B_SZ * NH), 256, 0, stream>>>(q_bf, ck_bf, vt_bf, attn_bf, S_LEN, CTX_LEN);
  GEMM(4, attn_bf, w_cao, ca_o_b, xb, xb, 0, 0, (int)NTOK, DIM, DIM);     // xb += (...)

  // ---- FFN + MoE ----
  ln_mod_kernel<0><<<(int)NTOK, 256, 0, stream>>>(xb, h_bf, modv, tmod, 4, 3, nullptr, nullptr);
  GEMM(2, h_bf, w_ffn1, ffn_b1, ff1_bf, nullptr, 0, 0, (int)NTOK, FFN_D, DIM);
  GEMM(0, ff1_bf, w_ffn2, ffn_b2, d_out, nullptr, 0, 0, (int)NTOK, DIM, FFN_D);
  for (int e = 0; e < NE; ++e)
    GEMM(5, h_bf, w_moe + (size_t)e * DD, moe_b + (size_t)e * DIM, d_out, nullptr, 0, e, (int)NTOK, DIM, DIM);
  final_add_kernel<<<(int)(NTOK * DIM / 4 / 256), 256, 0, stream>>>(xb, (float*)d_out, modv, tmod);
}

// Round 7
// 1620.688 us; speedup vs baseline: 1.1037x; 1.1037x over previous
//
#include <hip/hip_runtime.h>
#include <cstdint>
#include <cstddef>

#define B_SZ 2
#define S_LEN 2048
#define CTX_LEN 512
#define DIM 1536
#define NH 12
#define HD 128
#define FFN_D 6144
#define NE 4
#define TOPK 2

typedef unsigned short u16;
typedef __attribute__((ext_vector_type(8))) __bf16 bf16x8;
typedef __attribute__((ext_vector_type(4))) float f32x4;
typedef __attribute__((ext_vector_type(4))) unsigned short u16x4;

__device__ __forceinline__ u16 f2bf(float f) {
  union { float f; uint32_t u; } un; un.f = f;
  uint32_t u = un.u;
  u += 0x7fffu + ((u >> 16) & 1u);   // RNE
  return (u16)(u >> 16);
}

// async global->LDS, 16B per lane. LDS dest = wave-uniform base + lane*16.
__device__ __forceinline__ void gload_lds16(const u16* g, u16* l) {
  __builtin_amdgcn_global_load_lds(
      (const __attribute__((address_space(1))) void*)g,
      (__attribute__((address_space(3))) void*)l, 16, 0, 0);
}

// ---------------- f32 -> bf16 convert (weights, context) ----------------
__global__ void cvt_f32_bf16(const float* __restrict__ src, u16* __restrict__ dst, int n4) {
  int i = blockIdx.x * blockDim.x + threadIdx.x;
  int stride = gridDim.x * blockDim.x;
  for (; i < n4; i += stride) {
    f32x4 v = ((const f32x4*)src)[i];
    u16x4 o;
    o.x = f2bf(v.x); o.y = f2bf(v.y); o.z = f2bf(v.z); o.w = f2bf(v.w);
    ((u16x4*)dst)[i] = o;
  }
}

// ---------------- LayerNorm (+AdaLN modulation or affine) -> bf16 ----------------
template<int MODE>
__global__ __launch_bounds__(256) void ln_mod_kernel(
    const float* __restrict__ x, u16* __restrict__ out,
    const float* __restrict__ modv, const float* __restrict__ tmod,
    int scale_idx, int shift_idx,
    const float* __restrict__ w, const float* __restrict__ bvec)
{
  __shared__ float rbuf[8];
  int row = blockIdx.x;
  int b = row / S_LEN;
  const float* xr = x + (size_t)row * DIM;
  float v[6];
  float s = 0.f, s2 = 0.f;
#pragma unroll
  for (int j = 0; j < 6; ++j) {
    float t = xr[threadIdx.x + j * 256];
    v[j] = t; s += t; s2 += t * t;
  }
#pragma unroll
  for (int m = 32; m > 0; m >>= 1) { s += __shfl_xor(s, m, 64); s2 += __shfl_xor(s2, m, 64); }
  int wid = threadIdx.x >> 6;
  if ((threadIdx.x & 63) == 0) { rbuf[wid] = s; rbuf[4 + wid] = s2; }
  __syncthreads();
  s  = rbuf[0] + rbuf[1] + rbuf[2] + rbuf[3];
  s2 = rbuf[4] + rbuf[5] + rbuf[6] + rbuf[7];
  float mean = s * (1.f / DIM);
  float var  = s2 * (1.f / DIM) - mean * mean;
  float rstd = rsqrtf(var + 1e-6f);
#pragma unroll
  for (int j = 0; j < 6; ++j) {
    int n = threadIdx.x + j * 256;
    float y = (v[j] - mean) * rstd;
    float mul, add;
    if (MODE == 0) {
      mul = 1.f + modv[scale_idx * DIM + n] + tmod[(b * 6 + scale_idx) * DIM + n];
      add = modv[shift_idx * DIM + n] + tmod[(b * 6 + shift_idx) * DIM + n];
    } else {
      mul = w[n]; add = bvec[n];
    }
    out[(size_t)row * DIM + n] = f2bf(y * mul + add);
  }
}

// ---------------- RMSNorm (+optional RoPE, optional 1/sqrt(HD) fold) f32 -> bf16 ----------------
#define ATT_SC 0.08838834764831845f
template<int ROPE, int SCQ>
__global__ __launch_bounds__(256) void rms_rope_kernel(
    const float* __restrict__ x, const float* __restrict__ w,
    const float* __restrict__ cosb, const float* __restrict__ sinb,
    u16* __restrict__ out)
{
  __shared__ float rbuf[4];
  int row = blockIdx.x;
  const float* xr = x + (size_t)row * DIM;
  float v[6];
  float s2 = 0.f;
#pragma unroll
  for (int j = 0; j < 6; ++j) { float t = xr[threadIdx.x + j * 256]; v[j] = t; s2 += t * t; }
#pragma unroll
  for (int m = 32; m > 0; m >>= 1) s2 += __shfl_xor(s2, m, 64);
  int wid = threadIdx.x >> 6;
  if ((threadIdx.x & 63) == 0) rbuf[wid] = s2;
  __syncthreads();
  s2 = rbuf[0] + rbuf[1] + rbuf[2] + rbuf[3];
  float rs = rsqrtf(s2 * (1.f / DIM) + 1e-6f);
  const float osc = SCQ ? ATT_SC : 1.f;
  if (ROPE) {
    int spos = row & (S_LEN - 1);
#pragma unroll
    for (int j = 0; j < 3; ++j) {
      int pr = threadIdx.x + j * 256;          // pair index 0..767
      int head = pr >> 6, d = pr & 63;
      int n0 = head * HD + 2 * d;
      float xa = xr[n0] * rs * w[n0];
      float xb = xr[n0 + 1] * rs * w[n0 + 1];
      float c = cosb[spos * 64 + d], sn = sinb[spos * 64 + d];
      out[(size_t)row * DIM + n0]     = f2bf((xa * c - xb * sn) * osc);
      out[(size_t)row * DIM + n0 + 1] = f2bf((xa * sn + xb * c) * osc);
    }
  } else {
#pragma unroll
    for (int j = 0; j < 6; ++j) {
      int n = threadIdx.x + j * 256;
      out[(size_t)row * DIM + n] = f2bf(v[j] * rs * w[n] * osc);
    }
  }
}

// ---------------- bf16 MFMA GEMM (m97 structure): C = A @ W^T + bias ----------------
// 128x128 tile, BK=32, global_load_lds width-16 staging, linear LDS, 2 barriers/K-step.
// EPI 0: f32 out               EPI 1: bf16 out
// EPI 2: gelu bf16 out         EPI 3: f32 out = res + gate_mod*(v)
// EPI 4: f32 out = res + v     EPI 5: f32 out += moe_weight(row,expert)*v
template<int EPI>
__global__ __launch_bounds__(256) void gemm_bt(
    const u16* __restrict__ A, const u16* __restrict__ W,
    const float* __restrict__ bias, void* __restrict__ Cout,
    const float* __restrict__ res,
    const float* __restrict__ modv, const float* __restrict__ tmod, int mod_idx,
    const float* __restrict__ ew, const int* __restrict__ topk, int expert,
    int M, int N, int K)
{
  __shared__ __align__(16) u16 As[128 * 32];
  __shared__ __align__(16) u16 Bs[128 * 32];
  int tid = threadIdx.x;
  int wid = tid >> 6, lane = tid & 63;
  int wr = wid >> 1, wc = wid & 1;
  size_t brow = (size_t)blockIdx.x * 128, bcol = (size_t)blockIdx.y * 128;

  f32x4 acc[4][4];
#pragma unroll
  for (int i = 0; i < 4; ++i)
#pragma unroll
    for (int j = 0; j < 4; ++j) acc[i][j] = (f32x4){0.f, 0.f, 0.f, 0.f};

  // staging: wave w covers rows w*16..w*16+15 (issue 0) and +64 (issue 1); 4 lanes/row
  int srow = wid * 16 + (lane >> 2);
  int scol = (lane & 3) * 8;
  const u16* Ag0 = A + (brow + srow) * (size_t)K + scol;
  const u16* Wg0 = W + (bcol + srow) * (size_t)K + scol;
  u16* Al0 = &As[wid * 512];
  u16* Bl0 = &Bs[wid * 512];

  int cl = lane & 15, kk = (lane >> 4) * 8;

  for (int k0 = 0; k0 < K; k0 += 32) {
    gload_lds16(Ag0 + k0, Al0);
    gload_lds16(Ag0 + (size_t)64 * K + k0, Al0 + 2048);
    gload_lds16(Wg0 + k0, Bl0);
    gload_lds16(Wg0 + (size_t)64 * K + k0, Bl0 + 2048);
    __syncthreads();                 // drains vmcnt -> tiles visible
    bf16x8 af[4], bw[4];
#pragma unroll
    for (int i = 0; i < 4; ++i) {
      af[i] = *(const bf16x8*)&As[(wr * 64 + i * 16 + cl) * 32 + kk];
      bw[i] = *(const bf16x8*)&Bs[(wc * 64 + i * 16 + cl) * 32 + kk];
    }
#pragma unroll
    for (int mi = 0; mi < 4; ++mi)
#pragma unroll
      for (int ni = 0; ni < 4; ++ni)
        acc[mi][ni] = __builtin_amdgcn_mfma_f32_16x16x32_bf16(af[mi], bw[ni], acc[mi][ni], 0, 0, 0);
    __syncthreads();                 // all reads done before next stores
  }

  size_t row_base = brow + wr * 64;
  size_t col_base = bcol + wc * 64;
  int g4 = (lane >> 4) * 4;
#pragma unroll
  for (int ni = 0; ni < 4; ++ni) {
    size_t col = col_base + ni * 16 + cl;
    float bv = bias[col];
#pragma unroll
    for (int mi = 0; mi < 4; ++mi) {
#pragma unroll
      for (int r = 0; r < 4; ++r) {
        size_t row = row_base + mi * 16 + g4 + r;
        float val = acc[mi][ni][r] + bv;
        size_t idx = row * (size_t)N + col;
        if (EPI == 0) {
          ((float*)Cout)[idx] = val;
        } else if (EPI == 1) {
          ((u16*)Cout)[idx] = f2bf(val);
        } else if (EPI == 2) {
          float u = 0.7978845608028654f * (val + 0.044715f * val * val * val);
          float g = val * __builtin_amdgcn_rcpf(1.f + __expf(-2.f * u));
          ((u16*)Cout)[idx] = f2bf(g);
        } else if (EPI == 3) {
          int bb = (int)(row / S_LEN);
          float gate = modv[mod_idx * DIM + col] + tmod[((size_t)bb * 6 + mod_idx) * DIM + col];
          ((float*)Cout)[idx] = res[idx] + gate * val;
        } else if (EPI == 4) {
          ((float*)Cout)[idx] = res[idx] + val;
        } else if (EPI == 5) {
          float wsum = 0.f;
          int t0 = topk[row * TOPK], t1 = topk[row * TOPK + 1];
          if (t0 == expert) wsum += ew[row * TOPK];
          if (t1 == expert) wsum += ew[row * TOPK + 1];
          if (wsum != 0.f) ((float*)Cout)[idx] += wsum * val;
        }
      }
    }
  }
}

// ---------------- per-head V transpose: vt[b,h,d,s] = v[b,s,h*HD+d] ----------------
__global__ void transpose_v_kernel(const u16* __restrict__ v, u16* __restrict__ vt, int slen) {
  __shared__ u16 t[32][33];
  int bh = blockIdx.z;
  int b = bh / NH, h = bh % NH;
  int s0 = blockIdx.x * 32, d0 = blockIdx.y * 32;
  t[threadIdx.y][threadIdx.x] =
      v[((size_t)(b * slen) + s0 + threadIdx.y) * DIM + h * HD + d0 + threadIdx.x];
  __syncthreads();
  vt[((size_t)bh * HD + d0 + threadIdx.y) * slen + s0 + threadIdx.x] = t[threadIdx.x][threadIdx.y];
}

// ---------------- flash attention v2 ----------------
// 4 waves x 16 q-rows, KVBLK=64. K tile staged in LDS via global_load_lds,
// double-buffered, XOR-swizzled (pre-swizzled global src + swizzled ds_read).
// V read direct from pre-transposed vt (L2-hot). Q pre-scaled by 1/sqrt(HD).
__global__ __launch_bounds__(256) void flash_attn_kernel(
    const u16* __restrict__ q, const u16* __restrict__ k,
    const u16* __restrict__ vt, u16* __restrict__ out,
    int sq, int sk)
{
  __shared__ __align__(16) u16 Ks[2][64 * 128];   // 2 x 16KB, row=key (128 elems, swizzled)
  __shared__ __align__(16) u16 p_lds[4][16 * 72]; // per-wave P tile, pitch 72 (144B, 16B-aligned)
  int tid = threadIdx.x;
  int wid = tid >> 6, lane = tid & 63;
  int cl = lane & 15, g = lane >> 4;
  int bh = blockIdx.y, b = bh / NH, h = bh % NH;
  int q0 = blockIdx.x * 64 + wid * 16;

  const u16* qp = q + ((size_t)(b * sq) + q0 + cl) * DIM + h * HD + g * 8;
  bf16x8 aq[4];
#pragma unroll
  for (int c = 0; c < 4; ++c) aq[c] = *(const bf16x8*)(qp + c * 32);

  f32x4 o[8];
#pragma unroll
  for (int i = 0; i < 8; ++i) o[i] = (f32x4){0.f, 0.f, 0.f, 0.f};
  float m_r[4] = {-1e30f, -1e30f, -1e30f, -1e30f};
  float l_r[4] = {0.f, 0.f, 0.f, 0.f};

  const u16* kb = k + (size_t)(b * sk) * DIM + h * HD;
  const u16* vb = vt + (size_t)bh * HD * sk;

  // K staging map: issue i, wave w, lane l -> LDS byte ((i*4+w)*64 + l)*16
  //   row = (i*4+w)*4 + (l>>4); stored unit pos = l&15; data unit = (l&15)^(row&7)
  int u_sw = (lane & 15) ^ ((4 * (wid & 1) + (lane >> 4)) & 7);
  const u16* ksrc0 = kb + (size_t)(4 * wid + (lane >> 4)) * DIM + u_sw * 8;

  int nt = sk / 64;
  int x8 = (cl & 7) * 8;           // read-side swizzle (key&7)*8, key=ct*16+cl
  int buf = 0;

  // prologue: stage tile 0
#pragma unroll
  for (int i = 0; i < 4; ++i)
    gload_lds16(ksrc0 + (size_t)(16 * i) * DIM, &Ks[0][(i * 4 + wid) * 512]);

  for (int t = 0; t < nt; ++t) {
    __syncthreads();               // tile t resident; prior reads of buf^1 done
    if (t + 1 < nt) {
      const u16* s0 = ksrc0 + (size_t)(t + 1) * 64 * DIM;
#pragma unroll
      for (int i = 0; i < 4; ++i)
        gload_lds16(s0 + (size_t)(16 * i) * DIM, &Ks[buf ^ 1][(i * 4 + wid) * 512]);
    }
    const u16* Kt = Ks[buf];
    // ---- QK^T: S[16q x 64k] ----
    f32x4 s[4];
#pragma unroll
    for (int ct = 0; ct < 4; ++ct) {
      s[ct] = (f32x4){0.f, 0.f, 0.f, 0.f};
      int keyb = (ct * 16 + cl) * 128;
#pragma unroll
      for (int c = 0; c < 4; ++c) {
        bf16x8 kf = *(const bf16x8*)&Kt[keyb + ((c * 32 + g * 8) ^ x8)];
        s[ct] = __builtin_amdgcn_mfma_f32_16x16x32_bf16(aq[c], kf, s[ct], 0, 0, 0);
      }
    }
    // ---- online softmax over 64 keys ----
#pragma unroll
    for (int r = 0; r < 4; ++r) {
      float v0 = s[0][r], v1 = s[1][r], v2 = s[2][r], v3 = s[3][r];
      float pm = fmaxf(fmaxf(v0, v1), fmaxf(v2, v3));
#pragma unroll
      for (int msk = 8; msk > 0; msk >>= 1) pm = fmaxf(pm, __shfl_xor(pm, msk, 64));
      float mn = fmaxf(m_r[r], pm);
      float cf = __expf(m_r[r] - mn);
      float e0 = __expf(v0 - mn), e1 = __expf(v1 - mn);
      float e2 = __expf(v2 - mn), e3 = __expf(v3 - mn);
      float rsum = (e0 + e1) + (e2 + e3);
#pragma unroll
      for (int msk = 8; msk > 0; msk >>= 1) rsum += __shfl_xor(rsum, msk, 64);
      l_r[r] = l_r[r] * cf + rsum;
      m_r[r] = mn;
#pragma unroll
      for (int cc = 0; cc < 8; ++cc) o[cc][r] *= cf;
      int pr = (g * 4 + r) * 72;
      p_lds[wid][pr + cl]      = f2bf(e0);
      p_lds[wid][pr + 16 + cl] = f2bf(e1);
      p_lds[wid][pr + 32 + cl] = f2bf(e2);
      p_lds[wid][pr + 48 + cl] = f2bf(e3);
    }
    // wait for same-wave P writes before cross-lane read-back (in-order DS + compiler fence)
    asm volatile("s_waitcnt lgkmcnt(0)" ::: "memory");
    // ---- PV: O += P[16x64] @ V[64x128] ----
    bf16x8 ap0 = *(const bf16x8*)&p_lds[wid][cl * 72 + g * 8];
    bf16x8 ap1 = *(const bf16x8*)&p_lds[wid][cl * 72 + 32 + g * 8];
    const u16* vp = vb + (size_t)cl * sk + t * 64 + g * 8;
#pragma unroll
    for (int cc = 0; cc < 8; ++cc) {
      bf16x8 bv0 = *(const bf16x8*)(vp + (size_t)cc * 16 * sk);
      bf16x8 bv1 = *(const bf16x8*)(vp + (size_t)cc * 16 * sk + 32);
      o[cc] = __builtin_amdgcn_mfma_f32_16x16x32_bf16(ap0, bv0, o[cc], 0, 0, 0);
      o[cc] = __builtin_amdgcn_mfma_f32_16x16x32_bf16(ap1, bv1, o[cc], 0, 0, 0);
    }
    buf ^= 1;
  }
#pragma unroll
  for (int r = 0; r < 4; ++r) {
    float inv = 1.f / l_r[r];
    size_t orow = (size_t)(b * sq) + q0 + g * 4 + r;
#pragma unroll
    for (int cc = 0; cc < 8; ++cc)
      out[orow * DIM + h * HD + cc * 16 + cl] = f2bf(o[cc][r] * inv);
  }
}

// ---------------- final: out = xb + gate_mlp * (ff + moe) ----------------
__global__ __launch_bounds__(256) void final_add_kernel(
    const float* __restrict__ xb, float* __restrict__ out,
    const float* __restrict__ modv, const float* __restrict__ tmod)
{
  size_t i4 = (size_t)blockIdx.x * 256 + threadIdx.x;
  size_t base = i4 * 4;
  int n = (int)(base % DIM);
  int b = (int)(base / ((size_t)S_LEN * DIM));
  f32x4 xv = ((const f32x4*)xb)[i4];
  f32x4 ov = ((const f32x4*)out)[i4];
  f32x4 r;
#pragma unroll
  for (int j = 0; j < 4; ++j) {
    float gate = modv[5 * DIM + n + j] + tmod[((size_t)b * 6 + 5) * DIM + n + j];
    r[j] = xv[j] + gate * ov[j];
  }
  ((f32x4*)out)[i4] = r;
}

// =========================== host ===========================
extern "C" void kernel_launch(void* const* d_in, const int* in_sizes, int n_in,
                              void* d_out, int out_size, void* d_ws, size_t ws_size,
                              hipStream_t stream) {
  (void)in_sizes; (void)n_in; (void)out_size; (void)ws_size;
  const float* x_in   = (const float*)d_in[0];
  const float* ctx_in = (const float*)d_in[1];
  const float* tmod   = (const float*)d_in[2];
  const float* fcos   = (const float*)d_in[3];
  const float* fsin   = (const float*)d_in[4];
  const float* ew     = (const float*)d_in[5];
  const int*   topk   = (const int*)d_in[6];
  const float* sa_q_w = (const float*)d_in[7];
  const float* sa_q_b = (const float*)d_in[8];
  const float* sa_k_w = (const float*)d_in[9];
  const float* sa_k_b = (const float*)d_in[10];
  const float* sa_v_w = (const float*)d_in[11];
  const float* sa_v_b = (const float*)d_in[12];
  const float* sa_o_w = (const float*)d_in[13];
  const float* sa_o_b = (const float*)d_in[14];
  const float* sa_nq_w = (const float*)d_in[15];
  const float* sa_nk_w = (const float*)d_in[16];
  const float* ca_q_w = (const float*)d_in[17];
  const float* ca_q_b = (const float*)d_in[18];
  const float* ca_k_w = (const float*)d_in[19];
  const float* ca_k_b = (const float*)d_in[20];
  const float* ca_v_w = (const float*)d_in[21];
  const float* ca_v_b = (const float*)d_in[22];
  const float* ca_o_w = (const float*)d_in[23];
  const float* ca_o_b = (const float*)d_in[24];
  const float* ca_nq_w = (const float*)d_in[25];
  const float* ca_nk_w = (const float*)d_in[26];
  const float* norm3_w = (const float*)d_in[27];
  const float* norm3_b = (const float*)d_in[28];
  const float* ffn_w1 = (const float*)d_in[29];
  const float* ffn_b1 = (const float*)d_in[30];
  const float* ffn_w2 = (const float*)d_in[31];
  const float* ffn_b2 = (const float*)d_in[32];
  const float* modv   = (const float*)d_in[33];
  const float* moe_w  = (const float*)d_in[34];
  const float* moe_b  = (const float*)d_in[35];

  char* p = (char*)d_ws;
  auto alloc = [&](size_t bytes) { void* r = (void*)p; p += ((bytes + 255) & ~(size_t)255); return r; };
  const size_t NTOK = (size_t)B_SZ * S_LEN;          // 4096
  const size_t NCTX = (size_t)B_SZ * CTX_LEN;        // 1024
  const size_t DD = (size_t)DIM * DIM;

  // persistent weights (bf16)
  u16* w_saq  = (u16*)alloc(DD * 2);
  u16* w_sak  = (u16*)alloc(DD * 2);
  u16* w_sav  = (u16*)alloc(DD * 2);
  u16* w_sao  = (u16*)alloc(DD * 2);
  u16* w_caq  = (u16*)alloc(DD * 2);
  u16* w_cak  = (u16*)alloc(DD * 2);
  u16* w_cav  = (u16*)alloc(DD * 2);
  u16* w_cao  = (u16*)alloc(DD * 2);
  u16* w_ffn1 = (u16*)alloc((size_t)FFN_D * DIM * 2);
  u16* w_ffn2 = (u16*)alloc((size_t)DIM * FFN_D * 2);
  u16* w_moe  = (u16*)alloc((size_t)NE * DD * 2);
  // activations
  u16* h_bf   = (u16*)alloc(NTOK * DIM * 2);
  float* raw  = (float*)alloc(NTOK * DIM * 4);
  float* xb   = (float*)alloc(NTOK * DIM * 4);
  u16* q_bf   = (u16*)alloc(NTOK * DIM * 2);   // q,k,v,vt contiguous
  u16* k_bf   = (u16*)alloc(NTOK * DIM * 2);
  u16* v_bf   = (u16*)alloc(NTOK * DIM * 2);
  u16* vt_bf  = (u16*)alloc(NTOK * DIM * 2);
  u16* ctx_bf = (u16*)alloc(NCTX * DIM * 2);
  u16* ck_bf  = (u16*)alloc(NCTX * DIM * 2);
  u16* cv_bf  = (u16*)alloc(NCTX * DIM * 2);
  // aliases (live-range verified):
  u16* attn_bf = (u16*)raw;   // raw dead when attention output lands
  u16* ff1_bf  = q_bf;        // FFN phase: q..vt region dead

  auto cvtl = [&](const float* s_, u16* d_, size_t n) {
    int n4 = (int)(n / 4);
    int nb = (n4 + 255) / 256; if (nb > 2048) nb = 2048;
    cvt_f32_bf16<<<nb, 256, 0, stream>>>(s_, d_, n4);
  };
  auto GEMM = [&](int epi, const u16* Aa, const u16* Ww, const float* bb, void* Cc,
                  const float* rr, int mod_idx, int expert, int M, int N, int K) {
    dim3 g(M / 128, N / 128);
    switch (epi) {
      case 0: gemm_bt<0><<<g, 256, 0, stream>>>(Aa, Ww, bb, Cc, rr, modv, tmod, mod_idx, ew, topk, expert, M, N, K); break;
      case 1: gemm_bt<1><<<g, 256, 0, stream>>>(Aa, Ww, bb, Cc, rr, modv, tmod, mod_idx, ew, topk, expert, M, N, K); break;
      case 2: gemm_bt<2><<<g, 256, 0, stream>>>(Aa, Ww, bb, Cc, rr, modv, tmod, mod_idx, ew, topk, expert, M, N, K); break;
      case 3: gemm_bt<3><<<g, 256, 0, stream>>>(Aa, Ww, bb, Cc, rr, modv, tmod, mod_idx, ew, topk, expert, M, N, K); break;
      case 4: gemm_bt<4><<<g, 256, 0, stream>>>(Aa, Ww, bb, Cc, rr, modv, tmod, mod_idx, ew, topk, expert, M, N, K); break;
      case 5: gemm_bt<5><<<g, 256, 0, stream>>>(Aa, Ww, bb, Cc, rr, modv, tmod, mod_idx, ew, topk, expert, M, N, K); break;
    }
  };

  // weight/context conversion
  cvtl(sa_q_w, w_saq, DD); cvtl(sa_k_w, w_sak, DD); cvtl(sa_v_w, w_sav, DD); cvtl(sa_o_w, w_sao, DD);
  cvtl(ca_q_w, w_caq, DD); cvtl(ca_k_w, w_cak, DD); cvtl(ca_v_w, w_cav, DD); cvtl(ca_o_w, w_cao, DD);
  cvtl(ffn_w1, w_ffn1, (size_t)FFN_D * DIM);
  cvtl(ffn_w2, w_ffn2, (size_t)DIM * FFN_D);
  cvtl(moe_w, w_moe, (size_t)NE * DD);
  cvtl(ctx_in, ctx_bf, NCTX * DIM);

  // ---- self attention ----
  ln_mod_kernel<0><<<(int)NTOK, 256, 0, stream>>>(x_in, h_bf, modv, tmod, 1, 0, nullptr, nullptr);
  GEMM(0, h_bf, w_saq, sa_q_b, raw, nullptr, 0, 0, (int)NTOK, DIM, DIM);
  rms_rope_kernel<1, 1><<<(int)NTOK, 256, 0, stream>>>(raw, sa_nq_w, fcos, fsin, q_bf);  // q pre-scaled
  GEMM(0, h_bf, w_sak, sa_k_b, raw, nullptr, 0, 0, (int)NTOK, DIM, DIM);
  rms_rope_kernel<1, 0><<<(int)NTOK, 256, 0, stream>>>(raw, sa_nk_w, fcos, fsin, k_bf);
  GEMM(1, h_bf, w_sav, sa_v_b, v_bf, nullptr, 0, 0, (int)NTOK, DIM, DIM);
  transpose_v_kernel<<<dim3(S_LEN / 32, HD / 32, B_SZ * NH), dim3(32, 32), 0, stream>>>(v_bf, vt_bf, S_LEN);
  flash_attn_kernel<<<dim3(S_LEN / 64, B_SZ * NH), 256, 0, stream>>>(q_bf, k_bf, vt_bf, attn_bf, S_LEN, S_LEN);
  GEMM(3, attn_bf, w_sao, sa_o_b, xb, x_in, 2, 0, (int)NTOK, DIM, DIM);   // xb = x + gate_msa*(...)

  // ---- cross attention ----
  ln_mod_kernel<1><<<(int)NTOK, 256, 0, stream>>>(xb, h_bf, nullptr, nullptr, 0, 0, norm3_w, norm3_b);
  GEMM(0, h_bf, w_caq, ca_q_b, raw, nullptr, 0, 0, (int)NTOK, DIM, DIM);
  rms_rope_kernel<0, 1><<<(int)NTOK, 256, 0, stream>>>(raw, ca_nq_w, fcos, fsin, q_bf);  // q pre-scaled
  GEMM(0, ctx_bf, w_cak, ca_k_b, raw, nullptr, 0, 0, (int)NCTX, DIM, DIM);
  rms_rope_kernel<0, 0><<<(int)NCTX, 256, 0, stream>>>(raw, ca_nk_w, fcos, fsin, ck_bf);
  GEMM(1, ctx_bf, w_cav, ca_v_b, cv_bf, nullptr, 0, 0, (int)NCTX, DIM, DIM);
  transpose_v_kernel<<<dim3(CTX_LEN / 32, HD / 32, B_SZ * NH), dim3(32, 32), 0, stream>>>(cv_bf, vt_bf, CTX_LEN);
  flash_attn_kernel<<<dim3(S_LEN / 64, B_SZ * NH), 256, 0, stream>>>(q_bf, ck_bf, vt_bf, attn_bf, S_LEN, CTX_LEN);
  GEMM(4, attn_bf, w_cao, ca_o_b, xb, xb, 0, 0, (int)NTOK, DIM, DIM);     // xb += (...)

  // ---- FFN + MoE ----
  ln_mod_kernel<0><<<(int)NTOK, 256, 0, stream>>>(xb, h_bf, modv, tmod, 4, 3, nullptr, nullptr);
  GEMM(2, h_bf, w_ffn1, ffn_b1, ff1_bf, nullptr, 0, 0, (int)NTOK, FFN_D, DIM);
  GEMM(0, ff1_bf, w_ffn2, ffn_b2, d_out, nullptr, 0, 0, (int)NTOK, DIM, FFN_D);
  for (int e = 0; e < NE; ++e)
    GEMM(5, h_bf, w_moe + (size_t)e * DD, moe_b + (size_t)e * DIM, d_out, nullptr, 0, e, (int)NTOK, DIM, DIM);
  final_add_kernel<<<(int)(NTOK * DIM / 4 / 256), 256, 0, stream>>>(xb, (float*)d_out, modv, tmod);
}